// Round 3
// baseline (262.979 us; speedup 1.0000x reference)
//
#include <hip/hip_runtime.h>
#include <hip/hip_bf16.h>
#include <stdint.h>

#define B_DIM 32
#define N_DIM 1024
#define F_DIM 128
#define ALPHA 0.2f
#define NROWS (B_DIM * N_DIM)       // 32768
#define TAIL_ROWS 128               // rows handled by the recompute kernel
#define SCORE_BYTES ((size_t)(2 * NROWS) * sizeof(float))  // 256 KiB

// adj[0,0,0] == 1.0 always (self-loop on the diagonal).
//   f32 buffer:  first 32-bit word == 0x3F800000
//   bf16 buffer: first 32-bit word == (elem1<<16) | 0x3F80  (low half != 0)
__device__ __forceinline__ bool probe_is_f32(const void* adj) {
    return *(const uint32_t*)adj == 0x3F800000u;
}

// Where the [s_src | s_dst] f32 arrays live: caller-provided ws if it is big
// enough, otherwise the last 256 KiB of d_out (legal scratch; kernel C
// overwrites that region with final outputs afterwards).
template <bool F32>
__device__ __forceinline__ float* score_base(float* ws, int use_ws, void* out) {
    if (use_ws) return ws;
    const size_t out_bytes = (size_t)NROWS * N_DIM * (F32 ? 4 : 2);
    return (float*)((char*)out + out_bytes - SCORE_BYTES);
}

// ---------------------------------------------------------------------------
// Kernel A: per-node scores. One wave per row, 2 features/lane, shuffle-reduce.
// s_src[r] = feats[r,:].a[0:128], s_dst[r] = feats[r,:].a[128:256]
// ---------------------------------------------------------------------------
template <bool F32>
__device__ __forceinline__ void scores_body(
    const void* __restrict__ feats_v, const void* __restrict__ a_v,
    float* ws, int use_ws, void* out)
{
    float* base  = score_base<F32>(ws, use_ws, out);
    float* s_src = base;
    float* s_dst = base + NROWS;

    const int wid  = threadIdx.x >> 6;
    const int lane = threadIdx.x & 63;
    const int row  = blockIdx.x * 4 + wid;      // 0 .. NROWS-1
    const int f0   = lane * 2;                  // 0..126

    float x0, x1, a10, a11, a20, a21;
    if (F32) {
        const float* fp = (const float*)feats_v + (size_t)row * F_DIM + f0;
        const float* ap = (const float*)a_v;
        x0 = fp[0]; x1 = fp[1];
        a10 = ap[f0];         a11 = ap[f0 + 1];
        a20 = ap[F_DIM + f0]; a21 = ap[F_DIM + f0 + 1];
    } else {
        const __hip_bfloat16* fp = (const __hip_bfloat16*)feats_v + (size_t)row * F_DIM + f0;
        const __hip_bfloat16* ap = (const __hip_bfloat16*)a_v;
        x0  = __bfloat162float(fp[0]);           x1  = __bfloat162float(fp[1]);
        a10 = __bfloat162float(ap[f0]);          a11 = __bfloat162float(ap[f0 + 1]);
        a20 = __bfloat162float(ap[F_DIM + f0]);  a21 = __bfloat162float(ap[F_DIM + f0 + 1]);
    }

    float v1 = x0 * a10 + x1 * a11;
    float v2 = x0 * a20 + x1 * a21;
    #pragma unroll
    for (int off = 32; off > 0; off >>= 1) {
        v1 += __shfl_down(v1, off, 64);
        v2 += __shfl_down(v2, off, 64);
    }
    if (lane == 0) { s_src[row] = v1; s_dst[row] = v2; }
}

__global__ __launch_bounds__(256) void scores_kernel(
    const void* __restrict__ adj, const void* __restrict__ feats,
    const void* __restrict__ a, float* ws, int use_ws, void* out)
{
    if (probe_is_f32(adj)) scores_body<true>(feats, a, ws, use_ws, out);
    else                   scores_body<false>(feats, a, ws, use_ws, out);
}

// ---------------------------------------------------------------------------
// Shared softmax core: one 256-thread block handles one (b,i) row; thread t
// owns j = 4t..4t+3. Caller must have sdst[] staged in LDS and have issued
// __syncthreads() before calling.
// ---------------------------------------------------------------------------
template <bool F32>
__device__ __forceinline__ void softmax_core(
    const void* __restrict__ adj_v, void* __restrict__ out_v,
    int row, float ssrc, const float* sdst, float* wmax, float* wsum)
{
    const int tid  = threadIdx.x;
    const int lane = tid & 63;
    const int wid  = tid >> 6;

    bool valid[4];
    if (F32) {
        const uint4 av = ((const uint4*)((const float*)adj_v + (size_t)row * N_DIM))[tid];
        valid[0] = av.x != 0u; valid[1] = av.y != 0u;
        valid[2] = av.z != 0u; valid[3] = av.w != 0u;
    } else {
        const ushort4 av = ((const ushort4*)((const __hip_bfloat16*)adj_v + (size_t)row * N_DIM))[tid];
        valid[0] = av.x != 0; valid[1] = av.y != 0;
        valid[2] = av.z != 0; valid[3] = av.w != 0;
    }

    const int j0 = tid * 4;
    float e[4];
    float lmax = -1e30f;
    #pragma unroll
    for (int k = 0; k < 4; ++k) {
        float t = ssrc + sdst[j0 + k];
        t = (t >= 0.0f) ? t : ALPHA * t;       // LeakyReLU
        e[k] = t;
        if (valid[k]) lmax = fmaxf(lmax, t);
    }

    #pragma unroll
    for (int off = 32; off > 0; off >>= 1)
        lmax = fmaxf(lmax, __shfl_down(lmax, off, 64));
    if (lane == 0) wmax[wid] = lmax;
    __syncthreads();
    const float m = fmaxf(fmaxf(wmax[0], wmax[1]), fmaxf(wmax[2], wmax[3]));

    float p[4], lsum = 0.0f;
    #pragma unroll
    for (int k = 0; k < 4; ++k) {
        p[k] = valid[k] ? __expf(e[k] - m) : 0.0f;
        lsum += p[k];
    }
    #pragma unroll
    for (int off = 32; off > 0; off >>= 1)
        lsum += __shfl_down(lsum, off, 64);
    if (lane == 0) wsum[wid] = lsum;
    __syncthreads();
    const float inv = 1.0f / (wsum[0] + wsum[1] + wsum[2] + wsum[3]); // >=1 edge

    if (F32) {
        float4 o = make_float4(p[0] * inv, p[1] * inv, p[2] * inv, p[3] * inv);
        ((float4*)((float*)out_v + (size_t)row * N_DIM))[tid] = o;
    } else {
        union { ushort4 u4; __hip_bfloat16 h[4]; } o;
        #pragma unroll
        for (int k = 0; k < 4; ++k) o.h[k] = __float2bfloat16(p[k] * inv);
        ((ushort4*)((__hip_bfloat16*)out_v + (size_t)row * N_DIM))[tid] = o.u4;
    }
}

// ---------------------------------------------------------------------------
// Kernel B: rows 0 .. NROWS-TAIL_ROWS-1, reading stored scores. Never writes
// the tail of d_out, so stored scores stay intact while B runs.
// ---------------------------------------------------------------------------
template <bool F32>
__device__ __forceinline__ void main_body(
    const void* __restrict__ adj_v, float* ws, int use_ws, void* out_v)
{
    const int row = blockIdx.x;          // 0 .. NROWS-TAIL_ROWS-1
    const int b   = row >> 10;
    const int tid = threadIdx.x;

    float* base  = score_base<F32>(ws, use_ws, out_v);
    const float* s_src = base;
    const float* s_dst = base + NROWS + (size_t)b * N_DIM;

    __shared__ float sdst[N_DIM];
    __shared__ float wmax[4];
    __shared__ float wsum[4];

    #pragma unroll
    for (int k = 0; k < 4; ++k)
        sdst[tid + 256 * k] = s_dst[tid + 256 * k];
    const float ssrc = s_src[row];
    __syncthreads();

    softmax_core<F32>(adj_v, out_v, row, ssrc, sdst, wmax, wsum);
}

__global__ __launch_bounds__(256) void main_kernel(
    const void* __restrict__ adj, float* ws, int use_ws, void* out)
{
    if (probe_is_f32(adj)) main_body<true>(adj, ws, use_ws, out);
    else                   main_body<false>(adj, ws, use_ws, out);
}

// ---------------------------------------------------------------------------
// Kernel C: last TAIL_ROWS rows. Recomputes its scores directly from feats
// (no dependence on stored scores), then overwrites the tail of d_out —
// including the score scratch region — with final outputs.
// ---------------------------------------------------------------------------
template <bool F32>
__device__ __forceinline__ void tail_body(
    const void* __restrict__ adj_v, const void* __restrict__ feats_v,
    const void* __restrict__ a_v, void* __restrict__ out_v)
{
    const int row = NROWS - TAIL_ROWS + blockIdx.x;
    const int b   = row >> 10;           // = 31
    const int tid = threadIdx.x;

    __shared__ float sdst[N_DIM];
    __shared__ float ssrc_sh;
    __shared__ float wmax[4];
    __shared__ float wsum[4];

    // recompute s_dst[b, j] for j = 4t..4t+3 (feats[b] is L2-hot after A)
    #pragma unroll
    for (int k = 0; k < 4; ++k) {
        const int j = tid * 4 + k;
        float acc = 0.0f;
        if (F32) {
            const float* fp = (const float*)feats_v + ((size_t)b * N_DIM + j) * F_DIM;
            const float* ap = (const float*)a_v + F_DIM;
            #pragma unroll 8
            for (int f = 0; f < F_DIM; ++f) acc += fp[f] * ap[f];
        } else {
            const __hip_bfloat16* fp = (const __hip_bfloat16*)feats_v + ((size_t)b * N_DIM + j) * F_DIM;
            const __hip_bfloat16* ap = (const __hip_bfloat16*)a_v + F_DIM;
            #pragma unroll 8
            for (int f = 0; f < F_DIM; ++f)
                acc += __bfloat162float(fp[f]) * __bfloat162float(ap[f]);
        }
        sdst[j] = acc;
    }

    // s_src[row]: wave 0, 2 features/lane, shuffle-reduce
    if (tid < 64) {
        const int f0 = tid * 2;
        float x0, x1, a0, a1;
        if (F32) {
            const float* fp = (const float*)feats_v + (size_t)row * F_DIM + f0;
            const float* ap = (const float*)a_v;
            x0 = fp[0]; x1 = fp[1]; a0 = ap[f0]; a1 = ap[f0 + 1];
        } else {
            const __hip_bfloat16* fp = (const __hip_bfloat16*)feats_v + (size_t)row * F_DIM + f0;
            const __hip_bfloat16* ap = (const __hip_bfloat16*)a_v;
            x0 = __bfloat162float(fp[0]); x1 = __bfloat162float(fp[1]);
            a0 = __bfloat162float(ap[f0]); a1 = __bfloat162float(ap[f0 + 1]);
        }
        float v = x0 * a0 + x1 * a1;
        #pragma unroll
        for (int off = 32; off > 0; off >>= 1)
            v += __shfl_down(v, off, 64);
        if (tid == 0) ssrc_sh = v;
    }
    __syncthreads();

    softmax_core<F32>(adj_v, out_v, row, ssrc_sh, sdst, wmax, wsum);
}

__global__ __launch_bounds__(256) void tail_kernel(
    const void* __restrict__ adj, const void* __restrict__ feats,
    const void* __restrict__ a, void* __restrict__ out)
{
    if (probe_is_f32(adj)) tail_body<true>(adj, feats, a, out);
    else                   tail_body<false>(adj, feats, a, out);
}

extern "C" void kernel_launch(void* const* d_in, const int* in_sizes, int n_in,
                              void* d_out, int out_size, void* d_ws, size_t ws_size,
                              hipStream_t stream) {
    const void* adj   = d_in[0];   // [B,N,N]
    const void* feats = d_in[1];   // [B,N,F]
    const void* a     = d_in[2];   // [2F,1]

    // Never write outside the workspace we were given: use d_ws only if it
    // actually fits the 256 KiB score arrays; otherwise use the d_out tail.
    // ws_size is constant across calls -> identical work every call.
    const int use_ws = (ws_size >= SCORE_BYTES) ? 1 : 0;
    float* ws = (float*)d_ws;

    scores_kernel<<<NROWS / 4, 256, 0, stream>>>(adj, feats, a, ws, use_ws, d_out);
    main_kernel<<<NROWS - TAIL_ROWS, 256, 0, stream>>>(adj, ws, use_ws, d_out);
    tail_kernel<<<TAIL_ROWS, 256, 0, stream>>>(adj, feats, a, d_out);
}